// Round 4
// baseline (59.629 us; speedup 1.0000x reference)
//
#include <hip/hip_runtime.h>

#define NLEV 127.0f
#define QEPS 1e-8f
#define ABS_BLOCKS 1024

// ws layout (floats):
// [0..1023]      per-block |x| partial maxima
// [1024..1028]   C3 diag (= sfv of layer 3), len 5
// [1029..1161]   bpre = b / w_sf, flattened [l0:64 | l1:32 | l2:32 | l3:5]
// [1162..1801]   Cs[5][128]: row j = [C0[j][0..63] | C1[j][0..31] | C2[j][0..31]]
// [1802..1881]   T_lin[5][16] (s-independent composite linear map)
#define WS_PART 0
#define WS_C3   1024
#define WS_BPRE 1029
#define WS_CS   1162
#define WS_TLIN 1802

__device__ __forceinline__ float max4(float4 v) {
    return fmaxf(fmaxf(fabsf(v.x), fabsf(v.y)), fmaxf(fabsf(v.z), fabsf(v.w)));
}
__device__ __forceinline__ float clipr(float v) {
    return fminf(fmaxf(rintf(v), -NLEV), NLEV);
}

// Kernel 1: blocks 0..1023 do the |x| absmax scan; block 1024 does all
// s-independent weight composition (overlapped with the scan).
__global__ void __launch_bounds__(256) k1_absmax_compose(
        const float4* __restrict__ x4,
        const float* __restrict__ w0, const float* __restrict__ b0,
        const float* __restrict__ w2, const float* __restrict__ b2,
        const float* __restrict__ w4, const float* __restrict__ b4,
        const float* __restrict__ w6, const float* __restrict__ b6,
        float* __restrict__ ws, int n4) {
    __shared__ float sm[4];
    __shared__ float Wq[2048];          // max O*F = 32*64
    __shared__ float Rm[5 * 64], Rn[5 * 64], Cm[5 * 64];
    __shared__ float sfv[64];
    const int t = threadIdx.x;

    if (blockIdx.x < ABS_BLOCKS) {
        const int tid = blockIdx.x * 256 + t;
        const int stride = ABS_BLOCKS * 256;
        float m0 = 0.f, m1 = 0.f, m2 = 0.f, m3 = 0.f;
        int i = tid;
        for (; i + 3 * stride < n4; i += 4 * stride) {
            float4 a = x4[i];
            float4 b = x4[i + stride];
            float4 c = x4[i + 2 * stride];
            float4 d = x4[i + 3 * stride];
            m0 = fmaxf(m0, max4(a));
            m1 = fmaxf(m1, max4(b));
            m2 = fmaxf(m2, max4(c));
            m3 = fmaxf(m3, max4(d));
        }
        for (; i < n4; i += stride) m0 = fmaxf(m0, max4(x4[i]));
        float m = fmaxf(fmaxf(m0, m1), fmaxf(m2, m3));
        #pragma unroll
        for (int off = 32; off > 0; off >>= 1)
            m = fmaxf(m, __shfl_down(m, off, 64));
        if ((t & 63) == 0) sm[t >> 6] = m;
        __syncthreads();
        if (t == 0)
            ws[WS_PART + blockIdx.x] = fmaxf(fmaxf(sm[0], sm[1]), fmaxf(sm[2], sm[3]));
        return;
    }

    // ---- compose block (s-independent) ----
    // Layers L0..L3: (O,F) = (64,16) (32,64) (32,32) (5,32); processed 3 -> 0.
    const float* Wl[4] = {w0, w2, w4, w6};
    const float* Bl[4] = {b0, b2, b4, b6};
    const int Ol[4] = {64, 32, 32, 5};
    const int Fl[4] = {16, 64, 32, 32};
    const int bpre_off[4] = {WS_BPRE, WS_BPRE + 64, WS_BPRE + 96, WS_BPRE + 128};
    const int cs_base[4]  = {0, 64, 96, 0};  // [3] unused

    for (int L = 3; L >= 0; --L) {
        const int O = Ol[L], F = Fl[L];
        const float* W = Wl[L];
        const float* Bb = Bl[L];
        if (t < O) {
            float am = 0.f;
            for (int j = 0; j < F; ++j) am = fmaxf(am, fabsf(W[t * F + j]));
            float sf = fmaxf(am / NLEV, QEPS);
            sfv[t] = sf;
            ws[bpre_off[L] + t] = Bb[t] / sf;
        }
        __syncthreads();
        for (int i = t; i < O * F; i += 256)
            Wq[i] = clipr(W[i] / sfv[i / F]);
        __syncthreads();
        if (L == 3) {
            // Rm = D3 * Wq3  (5 x 32); C3 = diag(sfv3)
            for (int i = t; i < 5 * F; i += 256) Rm[i] = sfv[i / F] * Wq[i];
            if (t < 5) ws[WS_C3 + t] = sfv[t];
            __syncthreads();
        } else {
            // Cm = Rm (5xO) col-scaled by sfv  -> this layer's bias coefficient
            for (int i = t; i < 5 * O; i += 256) {
                int r = i / O, c0 = i % O;
                float v = Rm[r * O + c0] * sfv[c0];
                Cm[i] = v;
                ws[WS_CS + r * 128 + cs_base[L] + c0] = v;
            }
            __syncthreads();
            // Rn = Cm (5xO) * Wq (OxF) -> 5xF
            for (int i = t; i < 5 * F; i += 256) {
                int r = i / F, c0 = i % F;
                float acc = 0.f;
                for (int j = 0; j < O; ++j) acc += Cm[r * O + j] * Wq[j * F + c0];
                Rn[i] = acc;
            }
            __syncthreads();
            if (L == 0) {
                for (int i = t; i < 80; i += 256) ws[WS_TLIN + i] = Rn[i];  // T_lin 5x16
            } else {
                for (int i = t; i < 5 * F; i += 256) Rm[i] = Rn[i];
            }
            __syncthreads();
        }
    }
}

// Kernel 2: per-block prologue finalizes s-dependent constants redundantly
// (L2-hot, ~1-2us, overlapped across blocks), then the streaming main pass.
__global__ void __launch_bounds__(256) k2_main(const float4* __restrict__ x4,
                                               const float* __restrict__ ws,
                                               float4* __restrict__ out4, int Bq) {
    __shared__ float Msh[80];
    __shared__ float Cs[5 * 128];
    __shared__ float bi[133];
    __shared__ float cadd[5];
    __shared__ float red[4];
    __shared__ float s_sh;
    const int t = threadIdx.x;

    // s from the 1024 partials
    float pm = 0.f;
    for (int i = t; i < ABS_BLOCKS; i += 256) pm = fmaxf(pm, ws[WS_PART + i]);
    #pragma unroll
    for (int off = 32; off > 0; off >>= 1)
        pm = fmaxf(pm, __shfl_down(pm, off, 64));
    if ((t & 63) == 0) red[t >> 6] = pm;
    __syncthreads();
    if (t == 0) {
        float am = fmaxf(fmaxf(red[0], red[1]), fmaxf(red[2], red[3]));
        s_sh = fmaxf(am / NLEV, QEPS);
    }
    __syncthreads();
    const float s = s_sh;
    const float inv_s = 1.0f / s;

    for (int i = t; i < 133; i += 256) bi[i] = clipr(ws[WS_BPRE + i] * inv_s);
    for (int i = t; i < 640; i += 256) Cs[i] = ws[WS_CS + i];
    for (int i = t; i < 80; i += 256)  Msh[i] = ws[WS_TLIN + i] * s;
    __syncthreads();
    if (t < 5) {
        float acc = ws[WS_C3 + t] * bi[128 + t];
        for (int o = 0; o < 128; ++o) acc += Cs[t * 128 + o] * bi[o];
        cadd[t] = acc * s;
    }
    __syncthreads();

    const int tid = blockIdx.x * blockDim.x + t;
    const int stride = gridDim.x * blockDim.x;
    for (int grp = tid; grp < Bq; grp += stride) {
        const float4* xr = x4 + (size_t)grp * 16;
        float flat[20];
        #pragma unroll
        for (int r = 0; r < 4; ++r) {
            float q[16];
            #pragma unroll
            for (int v = 0; v < 4; ++v) {
                float4 vv = xr[r * 4 + v];
                q[v * 4 + 0] = fminf(fmaxf(rintf(vv.x * inv_s), -NLEV), NLEV);
                q[v * 4 + 1] = fminf(fmaxf(rintf(vv.y * inv_s), -NLEV), NLEV);
                q[v * 4 + 2] = fminf(fmaxf(rintf(vv.z * inv_s), -NLEV), NLEV);
                q[v * 4 + 3] = fminf(fmaxf(rintf(vv.w * inv_s), -NLEV), NLEV);
            }
            #pragma unroll
            for (int oo = 0; oo < 5; ++oo) {
                float acc = cadd[oo];
                #pragma unroll
                for (int i = 0; i < 16; ++i) acc = fmaf(q[i], Msh[oo * 16 + i], acc);
                flat[r * 5 + oo] = acc;
            }
        }
        float4* orow = out4 + (size_t)grp * 5;
        orow[0] = make_float4(flat[0],  flat[1],  flat[2],  flat[3]);
        orow[1] = make_float4(flat[4],  flat[5],  flat[6],  flat[7]);
        orow[2] = make_float4(flat[8],  flat[9],  flat[10], flat[11]);
        orow[3] = make_float4(flat[12], flat[13], flat[14], flat[15]);
        orow[4] = make_float4(flat[16], flat[17], flat[18], flat[19]);
    }
}

extern "C" void kernel_launch(void* const* d_in, const int* in_sizes, int n_in,
                              void* d_out, int out_size, void* d_ws, size_t ws_size,
                              hipStream_t stream) {
    const float* x  = (const float*)d_in[0];
    const float* w0 = (const float*)d_in[1];
    const float* b0 = (const float*)d_in[2];
    const float* w2 = (const float*)d_in[3];
    const float* b2 = (const float*)d_in[4];
    const float* w4 = (const float*)d_in[5];
    const float* b4 = (const float*)d_in[6];
    const float* w6 = (const float*)d_in[7];
    const float* b6 = (const float*)d_in[8];
    float* ws = (float*)d_ws;

    const int B  = in_sizes[0] / 16;
    const int n4 = B * 4;   // float4 elements of x
    const int Bq = B / 4;   // 4-row groups

    k1_absmax_compose<<<ABS_BLOCKS + 1, 256, 0, stream>>>(
        (const float4*)x, w0, b0, w2, b2, w4, b4, w6, b6, ws, n4);
    k2_main<<<1024, 256, 0, stream>>>((const float4*)x, ws, (float4*)d_out, Bq);
}

// Round 5
// 46.784 us; speedup vs baseline: 1.2746x; 1.2746x over previous
//
#include <hip/hip_runtime.h>

#define NLEV 127.0f
#define QEPS 1e-8f
#define ABS_BLOCKS 1024

// ws layout (floats):
// [1]            inv_s
// [2..81]        M[5][16] composite matrix (pre-scaled by s)
// [82..86]       c[5] composite bias (pre-scaled by s)
// [128..128+ABS_BLOCKS)  per-block |x| partial maxima

__device__ __forceinline__ float max4(float4 v) {
    return fmaxf(fmaxf(fabsf(v.x), fabsf(v.y)), fmaxf(fabsf(v.z), fabsf(v.w)));
}
__device__ __forceinline__ float clipr(float v) {
    return fminf(fmaxf(rintf(v), -NLEV), NLEV);
}

// ---- kernel 1: partial absmax, 8 loads in flight ----
__global__ void __launch_bounds__(256) absmax_part(const float4* __restrict__ x,
                                                   int n4, float* __restrict__ ws) {
    const int tid = blockIdx.x * 256 + threadIdx.x;
    const int stride = gridDim.x * 256;
    float m[8];
    #pragma unroll
    for (int k = 0; k < 8; ++k) m[k] = 0.f;
    int i = tid;
    for (; i + 7 * stride < n4; i += 8 * stride) {
        #pragma unroll
        for (int k = 0; k < 8; ++k) m[k] = fmaxf(m[k], max4(x[i + k * stride]));
    }
    for (; i < n4; i += stride) m[0] = fmaxf(m[0], max4(x[i]));
    float mm = fmaxf(fmaxf(fmaxf(m[0], m[1]), fmaxf(m[2], m[3])),
                     fmaxf(fmaxf(m[4], m[5]), fmaxf(m[6], m[7])));
    #pragma unroll
    for (int off = 32; off > 0; off >>= 1)
        mm = fmaxf(mm, __shfl_down(mm, off, 64));
    __shared__ float sm[4];
    if ((threadIdx.x & 63) == 0) sm[threadIdx.x >> 6] = mm;
    __syncthreads();
    if (threadIdx.x == 0)
        ws[128 + blockIdx.x] = fmaxf(fmaxf(sm[0], sm[1]), fmaxf(sm[2], sm[3]));
}

// ---- kernel 2: reduce partials -> s; quantize weights (reference-exact);
//      compose 4 affine layers into M[5][16], c[5] (pre-scaled by s) ----
__global__ void __launch_bounds__(256) prep_kernel(
        const float* __restrict__ w0, const float* __restrict__ b0,
        const float* __restrict__ w2, const float* __restrict__ b2,
        const float* __restrict__ w4, const float* __restrict__ b4,
        const float* __restrict__ w6, const float* __restrict__ b6,
        float* ws) {
    __shared__ float T[64][16], Tn[64][16];
    __shared__ float cc[64], cn[64], sfv[64], bi[64];
    __shared__ float Wq[64 * 64];
    __shared__ unsigned rmax[64];
    __shared__ float red[4];
    __shared__ float s_sh;
    const int t = threadIdx.x;

    float pm = 0.f;
    for (int i = t; i < ABS_BLOCKS; i += 256) pm = fmaxf(pm, ws[128 + i]);
    #pragma unroll
    for (int off = 32; off > 0; off >>= 1)
        pm = fmaxf(pm, __shfl_down(pm, off, 64));
    if ((t & 63) == 0) red[t >> 6] = pm;
    __syncthreads();
    if (t == 0) {
        float am = fmaxf(fmaxf(red[0], red[1]), fmaxf(red[2], red[3]));
        s_sh = fmaxf(am / NLEV, QEPS);
    }
    for (int i = t; i < 64 * 16; i += 256) {
        int r = i >> 4, ci = i & 15;
        T[r][ci] = (r == ci) ? 1.f : 0.f;
    }
    if (t < 64) cc[t] = 0.f;
    __syncthreads();
    const float s = s_sh;

    const float* Ws[4] = {w0, w2, w4, w6};
    const float* Bs[4] = {b0, b2, b4, b6};
    const int    Od[4] = {64, 32, 32, 5};
    const int    Fd[4] = {16, 64, 32, 32};

    for (int L = 0; L < 4; ++L) {
        const int O = Od[L], F = Fd[L];
        const float* W = Ws[L];
        const float* Bb = Bs[L];
        // parallel per-row absmax: coalesced float4 reads + LDS atomicMax on abs bits
        if (t < 64) rmax[t] = 0u;
        __syncthreads();
        const int nf4 = O * F / 4, f4row = F / 4;
        for (int i = t; i < nf4; i += 256) {
            float4 wv = ((const float4*)W)[i];
            atomicMax(&rmax[i / f4row], __float_as_uint(max4(wv)));
        }
        __syncthreads();
        if (t < O) {
            float sf = fmaxf(__uint_as_float(rmax[t]) / NLEV, QEPS);
            sfv[t] = sf;
            bi[t]  = clipr(Bb[t] / (sf * s));
        }
        __syncthreads();
        for (int i = t; i < O * F; i += 256)
            Wq[i] = clipr(W[i] / sfv[i / F]);
        __syncthreads();
        for (int i = t; i < O * 16; i += 256) {
            int o = i >> 4, col = i & 15;
            float acc = 0.f;
            #pragma unroll 8
            for (int j = 0; j < F; ++j) acc += Wq[o * F + j] * T[j][col];
            Tn[o][col] = acc * sfv[o];
        }
        if (t < O) {
            float acc = bi[t];
            #pragma unroll 8
            for (int j = 0; j < F; ++j) acc += Wq[t * F + j] * cc[j];
            cn[t] = acc * sfv[t];
        }
        __syncthreads();
        for (int i = t; i < O * 16; i += 256) T[i >> 4][i & 15] = Tn[i >> 4][i & 15];
        if (t < O) cc[t] = cn[t];
        __syncthreads();
    }
    if (t < 80) ws[2 + t] = T[t >> 4][t & 15] * s;
    if (t < 5)  ws[82 + t] = cc[t] * s;
    if (t == 0) ws[1] = 1.0f / s;
}

// ---- kernel 3: streaming main pass ----
// Lane t of a block handles segment v=t&3 of row lrow=t>>2 within a 64-row tile.
// Coalesced 1KB/wave loads; quad shfl-reduce; LDS output stage; coalesced
// float4 stores by 80 lanes. Double-buffered stage -> 1 barrier/tile.
__global__ void __launch_bounds__(256) main_kernel(const float4* __restrict__ x4,
                                                   const float* __restrict__ ws,
                                                   float4* __restrict__ out4,
                                                   int nTiles, int B,
                                                   float* __restrict__ out_tail) {
    __shared__ __align__(16) float ostage[640];
    const int t = threadIdx.x;
    const int v = t & 3;
    const int lrow = t >> 2;
    const float inv_s = ws[1];
    float Mreg[5][4], cadd[5];
    #pragma unroll
    for (int oo = 0; oo < 5; ++oo) {
        cadd[oo] = ws[82 + oo];
        #pragma unroll
        for (int j = 0; j < 4; ++j)
            Mreg[oo][j] = ws[2 + oo * 16 + v * 4 + j];
    }

    int parity = 0;
    int tile = blockIdx.x;
    float4 xv = make_float4(0.f, 0.f, 0.f, 0.f);
    if (tile < nTiles) xv = x4[(size_t)tile * 256 + t];
    for (; tile < nTiles; tile += gridDim.x, parity ^= 1) {
        const int nt = tile + gridDim.x;
        float4 xn = make_float4(0.f, 0.f, 0.f, 0.f);
        if (nt < nTiles) xn = x4[(size_t)nt * 256 + t];

        float q0 = fminf(fmaxf(rintf(xv.x * inv_s), -NLEV), NLEV);
        float q1 = fminf(fmaxf(rintf(xv.y * inv_s), -NLEV), NLEV);
        float q2 = fminf(fmaxf(rintf(xv.z * inv_s), -NLEV), NLEV);
        float q3 = fminf(fmaxf(rintf(xv.w * inv_s), -NLEV), NLEV);

        float* buf = ostage + (parity ? 320 : 0);
        float p[5];
        #pragma unroll
        for (int oo = 0; oo < 5; ++oo) {
            float acc = fmaf(q0, Mreg[oo][0],
                        fmaf(q1, Mreg[oo][1],
                        fmaf(q2, Mreg[oo][2], q3 * Mreg[oo][3])));
            acc += __shfl_xor(acc, 1, 64);
            acc += __shfl_xor(acc, 2, 64);
            p[oo] = acc;
        }
        if (v == 0) {
            #pragma unroll
            for (int oo = 0; oo < 5; ++oo) buf[lrow * 5 + oo] = p[oo] + cadd[oo];
        }
        __syncthreads();
        if (t < 80) out4[(size_t)tile * 80 + t] = ((const float4*)buf)[t];
        xv = xn;
    }

    // tail rows (B not multiple of 64) — scalar path, block 0 only
    const int tailStart = nTiles * 64;
    if (blockIdx.x == 0 && tailStart < B) {
        for (int r = tailStart + t; r < B; r += 256) {
            const float* xr = (const float*)x4 + (size_t)r * 16;
            float q[16];
            #pragma unroll
            for (int i = 0; i < 16; ++i)
                q[i] = fminf(fmaxf(rintf(xr[i] * inv_s), -NLEV), NLEV);
            #pragma unroll
            for (int oo = 0; oo < 5; ++oo) {
                float acc = ws[82 + oo];
                for (int i = 0; i < 16; ++i) acc = fmaf(q[i], ws[2 + oo * 16 + i], acc);
                out_tail[(size_t)r * 5 + oo] = acc;
            }
        }
    }
}

extern "C" void kernel_launch(void* const* d_in, const int* in_sizes, int n_in,
                              void* d_out, int out_size, void* d_ws, size_t ws_size,
                              hipStream_t stream) {
    const float* x  = (const float*)d_in[0];
    const float* w0 = (const float*)d_in[1];
    const float* b0 = (const float*)d_in[2];
    const float* w2 = (const float*)d_in[3];
    const float* b2 = (const float*)d_in[4];
    const float* w4 = (const float*)d_in[5];
    const float* b4 = (const float*)d_in[6];
    const float* w6 = (const float*)d_in[7];
    const float* b6 = (const float*)d_in[8];
    float* ws = (float*)d_ws;

    const int B  = in_sizes[0] / 16;
    const int n4 = B * 4;        // float4 elements of x
    const int nTiles = B / 64;   // 64-row tiles

    absmax_part<<<ABS_BLOCKS, 256, 0, stream>>>((const float4*)x, n4, ws);
    prep_kernel<<<1, 256, 0, stream>>>(w0, b0, w2, b2, w4, b4, w6, b6, ws);
    main_kernel<<<1024, 256, 0, stream>>>((const float4*)x, ws, (float4*)d_out,
                                          nTiles, B, (float*)d_out);
}